// Round 3
// baseline (148.885 us; speedup 1.0000x reference)
//
#include <hip/hip_runtime.h>

// VQ-VAE VectorQuantizer forward, MI355X (gfx950), fp32.
// N=32768 points x D=64 dims, K=1024 codes.
// Out: [0]=loss, [1..QE]=quantized [B,D,H,W], [+..]=indices [B,H*W] as f32.
//
// R3: LDS-instruction-throughput fix. R2 was bound by 12288 ds_read_b128/CU
// (3 per 32 FMA). Now: 512 blocks x 256 threads (2 blocks/CU), per-thread
// 8x16 register tile -> 6 b128 per 128 FMA (3072/CU, under the 65K-cyc FMA
// floor). e staged transposed in 16-d slabs with quad-swizzle for bank
// balance. Dot chains keep R2's exact d-sequential fmaf rounding.

constexpr int D_   = 64;
constexpr int HW   = 1024;     // H*W
constexpr int K_   = 1024;
constexpr int PTS  = 64;       // points per block
constexpr int SP   = 68;       // xT row stride (floats)
constexpr int SEK  = 516;      // eT slab row stride (floats), 512 + 4 pad
constexpr int QE   = 2097152;
constexpr int IDX_OFF = 1 + QE;

__global__ __launch_bounds__(256, 2) void vq_main_kernel(
    const float* __restrict__ in, const float* __restrict__ emb,
    float* __restrict__ out, float* __restrict__ loss_acc,
    unsigned* __restrict__ cnt) {
  __shared__ float xT[D_ * SP];      // [d][p]  17.4 KB; later holds ST values
  __shared__ float eTs[16 * SEK];    // slab [16 d][512 k, swizzled]  33 KB
  __shared__ float e2s[K_];
  __shared__ float x2s[PTS];
  __shared__ int   idx_sel[PTS];
  __shared__ float redbuf[4];

  const int t   = threadIdx.x;
  const int kg  = t & 31;            // code group: 16 codes per pass
  const int ptg = t >> 5;            // point group: 8 points
  const int blk = blockIdx.x;
  const int b   = blk >> 4;          // 16 blocks per image (1024 hw / 64)
  const int hw0 = (blk & 15) * PTS;
  const float* inb = in + b * (D_ * HW) + hw0;

  // ---- stage x tile -> xT[d][p] (coalesced float4; b128 LDS writes) ----
#pragma unroll
  for (int i = 0; i < 4; ++i) {
    int fi = t + i * 256;                 // 0..1023
    int d  = fi >> 4, p4 = fi & 15;
    *(float4*)(&xT[d * SP + p4 * 4]) = *(const float4*)(inb + d * HW + p4 * 4);
  }

  // ---- e2s: 4 codes/thread, body identical to R2 (rounding!) ----
#pragma unroll
  for (int c = 0; c < 4; ++c) {
    int k = t + c * 256;
    const float4* e4 = (const float4*)(emb + k * 64);
    float s = 0.f;
#pragma unroll
    for (int q = 0; q < 16; ++q) {
      float4 v = e4[q];
      s += v.x * v.x; s += v.y * v.y; s += v.z * v.z; s += v.w * v.w;
    }
    e2s[k] = s;
  }
  __syncthreads();

  // ---- x2[p] (sequential d fmaf chain — identical to R2) ----
  if (t < PTS) {
    float s = 0.f;
#pragma unroll 8
    for (int d = 0; d < D_; ++d) { float xv = xT[d * SP + t]; s = fmaf(xv, xv, s); }
    x2s[t] = s;
  }
  __syncthreads();

  float x2r[8];
  {
    float4 xa = *(const float4*)&x2s[ptg * 8];
    float4 xb = *(const float4*)&x2s[ptg * 8 + 4];
    x2r[0]=xa.x; x2r[1]=xa.y; x2r[2]=xa.z; x2r[3]=xa.w;
    x2r[4]=xb.x; x2r[5]=xb.y; x2r[6]=xb.z; x2r[7]=xb.w;
  }

  // e-frag column offsets: quad-swizzle P(kg,q) = ((kg+q)&7) + 8*((kg>>3)+4q)
  int eoff[4];
#pragma unroll
  for (int q = 0; q < 4; ++q)
    eoff[q] = 4 * (((kg + q) & 7) + 8 * ((kg >> 3) + 4 * q));

  float minv[8]; int mini[8];
#pragma unroll
  for (int i = 0; i < 8; ++i) { minv[i] = 3.4e38f; mini[i] = 0; }

  // ---- 2 passes x 512 codes; 4 slabs of 16 dims each; acc over full d ----
#pragma unroll 1
  for (int pass = 0; pass < 2; ++pass) {
    float acc[8][16];
#pragma unroll
    for (int i = 0; i < 8; ++i)
#pragma unroll
      for (int j = 0; j < 16; ++j) acc[i][j] = 0.f;

#pragma unroll 1
    for (int s = 0; s < 4; ++s) {
      __syncthreads();   // previous slab's reads done
      // stage slab: codes 2t,2t+1, dims s*16..s*16+15 -> eTs[dd][C], b64 writes
      {
        int c0 = 2 * t;
        int kgs = c0 >> 4, qs = (c0 >> 2) & 3, js = c0 & 3;
        int Cc = 4 * (((kgs + qs) & 7) + 8 * ((kgs >> 3) + 4 * qs)) + js;
        const float4* ga = (const float4*)(emb + (pass * 512 + c0) * 64 + s * 16);
        const float4* gb = (const float4*)(emb + (pass * 512 + c0 + 1) * 64 + s * 16);
        float4 a[4], bb[4];
#pragma unroll
        for (int r = 0; r < 4; ++r) { a[r] = ga[r]; bb[r] = gb[r]; }
#pragma unroll
        for (int r = 0; r < 4; ++r) {
          float av[4] = {a[r].x, a[r].y, a[r].z, a[r].w};
          float bv[4] = {bb[r].x, bb[r].y, bb[r].z, bb[r].w};
#pragma unroll
          for (int jd = 0; jd < 4; ++jd)
            *(float2*)(&eTs[(r * 4 + jd) * SEK + Cc]) = make_float2(av[jd], bv[jd]);
        }
      }
      __syncthreads();

      // compute 16 dims: per d, 6 b128 reads feed 128 FMA
#pragma unroll 4
      for (int dd = 0; dd < 16; ++dd) {
        int drow = dd * SEK;
        int dg   = s * 16 + dd;
        float4 xa = *(const float4*)&xT[dg * SP + ptg * 8];
        float4 xb = *(const float4*)&xT[dg * SP + ptg * 8 + 4];
        float4 e0 = *(const float4*)&eTs[drow + eoff[0]];
        float4 e1 = *(const float4*)&eTs[drow + eoff[1]];
        float4 e2 = *(const float4*)&eTs[drow + eoff[2]];
        float4 e3 = *(const float4*)&eTs[drow + eoff[3]];
        float xf[8]  = {xa.x, xa.y, xa.z, xa.w, xb.x, xb.y, xb.z, xb.w};
        float ef[16] = {e0.x, e0.y, e0.z, e0.w, e1.x, e1.y, e1.z, e1.w,
                        e2.x, e2.y, e2.z, e2.w, e3.x, e3.y, e3.z, e3.w};
#pragma unroll
        for (int i = 0; i < 8; ++i)
#pragma unroll
          for (int j = 0; j < 16; ++j)
            acc[i][j] = fmaf(xf[i], ef[j], acc[i][j]);
      }
    }

    // fold: u = fl(fl(x2 - 2*dot) + e2) — identical expression/order to R2
    float e2f[16];
    {
      const float4* p4 = (const float4*)&e2s[pass * 512 + kg * 16];
#pragma unroll
      for (int q = 0; q < 4; ++q) {
        float4 v = p4[q];
        e2f[q*4+0]=v.x; e2f[q*4+1]=v.y; e2f[q*4+2]=v.z; e2f[q*4+3]=v.w;
      }
    }
#pragma unroll
    for (int j = 0; j < 16; ++j) {
      int cg = pass * 512 + kg * 16 + j;   // ascending within thread
      float e2v = e2f[j];
#pragma unroll
      for (int i = 0; i < 8; ++i) {
        float u = fmaf(-2.f, acc[i][j], x2r[i]) + e2v;
        if (u < minv[i]) { minv[i] = u; mini[i] = cg; }
      }
    }
  }

  // ---- cross-lane argmin over the 32 kg lanes sharing each point group ----
#pragma unroll
  for (int i = 0; i < 8; ++i) {
    float v = minv[i]; int ix = mini[i];
#pragma unroll
    for (int off = 1; off < 32; off <<= 1) {
      float vo = __shfl_xor(v, off);
      int   io = __shfl_xor(ix, off);
      if (vo < v || (vo == v && io < ix)) { v = vo; ix = io; }  // tie -> lower idx
    }
    if (kg == 0) idx_sel[ptg * 8 + i] = ix;
  }
  __syncthreads();

  if (t < PTS) out[IDX_OFF + blk * PTS + t] = (float)idx_sel[t];

  // ---- gather codes, loss partial, overwrite xT with x + (q - x) ----
  float lp = 0.f;
#pragma unroll
  for (int i = 0; i < 4; ++i) {
    int fi = t + i * 256;                 // 0..1023
    int p = fi & 63, qd = fi >> 6;        // p contiguous per wave
    int cidx = idx_sel[p];
    float4 q = *(const float4*)(emb + cidx * 64 + qd * 4);
    float xv0 = xT[(qd * 4 + 0) * SP + p];
    float xv1 = xT[(qd * 4 + 1) * SP + p];
    float xv2 = xT[(qd * 4 + 2) * SP + p];
    float xv3 = xT[(qd * 4 + 3) * SP + p];
    float d0 = q.x - xv0, d1 = q.y - xv1, d2 = q.z - xv2, d3 = q.w - xv3;
    lp = fmaf(d0, d0, lp); lp = fmaf(d1, d1, lp);
    lp = fmaf(d2, d2, lp); lp = fmaf(d3, d3, lp);
    xT[(qd * 4 + 0) * SP + p] = xv0 + d0;
    xT[(qd * 4 + 1) * SP + p] = xv1 + d1;
    xT[(qd * 4 + 2) * SP + p] = xv2 + d2;
    xT[(qd * 4 + 3) * SP + p] = xv3 + d3;
  }

  // loss: wave -> block -> one device atomic; last block finalizes out[0]
#pragma unroll
  for (int off = 1; off < 64; off <<= 1) lp += __shfl_xor(lp, off);
  if ((t & 63) == 0) redbuf[t >> 6] = lp;
  __syncthreads();   // also orders xT rewrites before the stores below
  if (t == 0) {
    atomicAdd(loss_acc, redbuf[0] + redbuf[1] + redbuf[2] + redbuf[3]);
    __threadfence();
    unsigned old = atomicAdd(cnt, 1u);
    if (old == 511u) {
      __threadfence();
      float total = atomicAdd(loss_acc, 0.0f);  // coherent read-back
      float m = total * (1.0f / 2097152.0f);
      out[0] = m + 0.25f * m;                   // ref op order
    }
  }

  // quantized output [B,D,H,W]: scalar coalesced stores (out+1 is 4B-aligned)
  float* outq = out + 1 + b * (D_ * HW) + hw0;
#pragma unroll
  for (int i = 0; i < 16; ++i) {
    int oi = t + i * 256;                 // 0..4095
    int d = oi >> 6, p = oi & 63;
    outq[d * HW + p] = xT[d * SP + p];
  }
}

extern "C" void kernel_launch(void* const* d_in, const int* in_sizes, int n_in,
                              void* d_out, int out_size, void* d_ws, size_t ws_size,
                              hipStream_t stream) {
  const float* in  = (const float*)d_in[0];
  const float* emb = (const float*)d_in[1];
  float* out = (float*)d_out;
  float* loss_acc = (float*)d_ws;                 // ws[0]
  unsigned* cnt   = (unsigned*)d_ws + 4;          // ws[4]

  hipMemsetAsync(d_ws, 0, 64, stream);            // zero accumulator + counter
  vq_main_kernel<<<512, 256, 0, stream>>>(in, emb, out, loss_acc, cnt);
}

// Round 4
// 138.904 us; speedup vs baseline: 1.0719x; 1.0719x over previous
//
#include <hip/hip_runtime.h>

// VQ-VAE VectorQuantizer forward, MI355X (gfx950), fp32.
// N=32768 points x D=64 dims, K=1024 codes.
// Out: [0]=loss, [1..QE]=quantized [B,D,H,W], [+..]=indices [B,H*W] as f32.
//
// R4: 8x8 per-thread tile (acc=64 VGPR -> no spill, unlike R3's 8x16 which
// the compiler spilled at VGPR_Count=108). Grid 256 x 512 thr (8 waves/CU),
// 128 pts/block, 4 chunks of 256 codes, register prefetch of next e-chunk.
// LDS model: r=16 FMA-inst/b128 -> 98K cyc/CU vs 65.5K FMA floor.
// All per-(point,code) math keeps R1's exact fmaf rounding (absmax 0).

constexpr int D_   = 64;
constexpr int HW   = 1024;     // H*W
constexpr int K_   = 1024;
constexpr int PTS  = 128;      // points per block
constexpr int SP   = 132;      // xT row stride (floats)
constexpr int SEC  = 260;      // eT row stride (floats)
constexpr int CK   = 256;      // codes per chunk
constexpr int QE   = 2097152;
constexpr int IDX_OFF = 1 + QE;

__global__ __launch_bounds__(512, 2) void vq_main_kernel(
    const float* __restrict__ in, const float* __restrict__ emb,
    float* __restrict__ out, float* __restrict__ loss_acc,
    unsigned* __restrict__ cnt) {
  __shared__ float xT[D_ * SP];      // [d][p] 33.8 KB; later holds ST values
  __shared__ float eTs[D_ * SEC];    // [d][k_local] 66.6 KB
  __shared__ float e2s[K_];
  __shared__ float x2s[PTS];
  __shared__ int   idx_sel[PTS];
  __shared__ float redbuf[8];

  const int t   = threadIdx.x;
  const int kg  = t & 31;            // code group: 8 codes
  const int ptg = t >> 5;            // point group: 8 points (16 groups)
  const int blk = blockIdx.x;
  const int b   = blk >> 3;          // 8 blocks per image
  const int hw0 = (blk & 7) * PTS;
  const float* inb = in + b * (D_ * HW) + hw0;

  // staging role: thread handles code (chunk-local) kl, dim-half h
  const int kl = t >> 1;             // 0..255
  const int h  = t & 1;              // dims h*32 .. h*32+31

  // ---- stage x tile -> xT[d][p] (coalesced float4) ----
#pragma unroll
  for (int i = 0; i < 4; ++i) {
    int fi = t + i * 512;                 // 0..2047
    int d  = fi >> 5, p4 = fi & 31;
    *(float4*)(&xT[d * SP + p4 * 4]) = *(const float4*)(inb + d * HW + p4 * 4);
  }

  // ---- e2s: 2 codes/thread, body identical to R1/R2 (rounding!) ----
#pragma unroll
  for (int c = 0; c < 2; ++c) {
    int k = t + c * 512;
    const float4* e4 = (const float4*)(emb + k * 64);
    float s = 0.f;
#pragma unroll
    for (int q = 0; q < 16; ++q) {
      float4 v = e4[q];
      s += v.x * v.x; s += v.y * v.y; s += v.z * v.z; s += v.w * v.w;
    }
    e2s[k] = s;
  }

  // ---- prefetch + stage chunk 0 ----
  float4 pf[8];
  {
    const float4* g = (const float4*)(emb + kl * 64 + h * 32);
#pragma unroll
    for (int r = 0; r < 8; ++r) pf[r] = g[r];
#pragma unroll
    for (int r = 0; r < 8; ++r) {
      int d = h * 32 + r * 4;
      eTs[(d + 0) * SEC + kl] = pf[r].x;   // banks (4d+kl)%32: 2-way = free
      eTs[(d + 1) * SEC + kl] = pf[r].y;
      eTs[(d + 2) * SEC + kl] = pf[r].z;
      eTs[(d + 3) * SEC + kl] = pf[r].w;
    }
  }
  __syncthreads();

  // ---- x2[p] (sequential d fmaf chain — identical to R1/R2) ----
  if (t < PTS) {
    float s = 0.f;
#pragma unroll 8
    for (int d = 0; d < D_; ++d) { float xv = xT[d * SP + t]; s = fmaf(xv, xv, s); }
    x2s[t] = s;
  }
  __syncthreads();

  float x2r[8];
  {
    float4 xa = *(const float4*)&x2s[ptg * 8];
    float4 xb = *(const float4*)&x2s[ptg * 8 + 4];
    x2r[0]=xa.x; x2r[1]=xa.y; x2r[2]=xa.z; x2r[3]=xa.w;
    x2r[4]=xb.x; x2r[5]=xb.y; x2r[6]=xb.z; x2r[7]=xb.w;
  }

  float minv[8]; int mini[8];
#pragma unroll
  for (int i = 0; i < 8; ++i) { minv[i] = 3.4e38f; mini[i] = 0; }

  // ---- K loop: 4 chunks of 256 codes ----
#pragma unroll 1
  for (int c = 0; c < 4; ++c) {
    // prefetch next chunk into regs (hidden under compute below)
    if (c < 3) {
      const float4* g = (const float4*)(emb + ((c + 1) * CK + kl) * 64 + h * 32);
#pragma unroll
      for (int r = 0; r < 8; ++r) pf[r] = g[r];
    }

    float acc[8][8];
#pragma unroll
    for (int i = 0; i < 8; ++i)
#pragma unroll
      for (int j = 0; j < 8; ++j) acc[i][j] = 0.f;

#pragma unroll 2
    for (int d = 0; d < D_; ++d) {
      float4 xa = *(const float4*)&xT[d * SP + ptg * 8];        // 32-way bcast
      float4 xb = *(const float4*)&xT[d * SP + ptg * 8 + 4];
      float4 e0 = *(const float4*)&eTs[d * SEC + kg * 8];
      float4 e1 = *(const float4*)&eTs[d * SEC + kg * 8 + 4];
      float xf[8] = {xa.x, xa.y, xa.z, xa.w, xb.x, xb.y, xb.z, xb.w};
      float ef[8] = {e0.x, e0.y, e0.z, e0.w, e1.x, e1.y, e1.z, e1.w};
#pragma unroll
      for (int i = 0; i < 8; ++i)
#pragma unroll
        for (int j = 0; j < 8; ++j)
          acc[i][j] = fmaf(xf[i], ef[j], acc[i][j]);
    }

    // fold: u = fl(fl(x2 - 2*dot) + e2) — identical expression/order to R1/R2
    float e2f[8];
    {
      const float4* p4 = (const float4*)&e2s[c * CK + kg * 8];
      float4 v0 = p4[0], v1 = p4[1];
      e2f[0]=v0.x; e2f[1]=v0.y; e2f[2]=v0.z; e2f[3]=v0.w;
      e2f[4]=v1.x; e2f[5]=v1.y; e2f[6]=v1.z; e2f[7]=v1.w;
    }
#pragma unroll
    for (int j = 0; j < 8; ++j) {
      int cg = c * CK + kg * 8 + j;        // ascending within thread
      float e2v = e2f[j];
#pragma unroll
      for (int i = 0; i < 8; ++i) {
        float u = fmaf(-2.f, acc[i][j], x2r[i]) + e2v;
        if (u < minv[i]) { minv[i] = u; mini[i] = cg; }
      }
    }

    if (c < 3) {
      __syncthreads();   // all waves done reading eTs chunk c
#pragma unroll
      for (int r = 0; r < 8; ++r) {
        int d = h * 32 + r * 4;
        eTs[(d + 0) * SEC + kl] = pf[r].x;
        eTs[(d + 1) * SEC + kl] = pf[r].y;
        eTs[(d + 2) * SEC + kl] = pf[r].z;
        eTs[(d + 3) * SEC + kl] = pf[r].w;
      }
      __syncthreads();
    }
  }

  // ---- cross-lane argmin over the 32 kg lanes sharing each point group ----
#pragma unroll
  for (int i = 0; i < 8; ++i) {
    float v = minv[i]; int ix = mini[i];
#pragma unroll
    for (int off = 1; off < 32; off <<= 1) {
      float vo = __shfl_xor(v, off);
      int   io = __shfl_xor(ix, off);
      if (vo < v || (vo == v && io < ix)) { v = vo; ix = io; }  // tie -> lower idx
    }
    if (kg == 0) idx_sel[ptg * 8 + i] = ix;
  }
  __syncthreads();

  if (t < PTS) out[IDX_OFF + blk * PTS + t] = (float)idx_sel[t];

  // ---- gather codes, loss partial, overwrite xT with x + (q - x) ----
  float lp = 0.f;
#pragma unroll
  for (int i = 0; i < 4; ++i) {
    int fi = t + i * 512;                 // 0..2047
    int p = fi & 127, qd = fi >> 7;       // p contiguous per wave
    int cidx = idx_sel[p];
    float4 q = *(const float4*)(emb + cidx * 64 + qd * 4);
    float xv0 = xT[(qd * 4 + 0) * SP + p];
    float xv1 = xT[(qd * 4 + 1) * SP + p];
    float xv2 = xT[(qd * 4 + 2) * SP + p];
    float xv3 = xT[(qd * 4 + 3) * SP + p];
    float d0 = q.x - xv0, d1 = q.y - xv1, d2 = q.z - xv2, d3 = q.w - xv3;
    lp = fmaf(d0, d0, lp); lp = fmaf(d1, d1, lp);
    lp = fmaf(d2, d2, lp); lp = fmaf(d3, d3, lp);
    xT[(qd * 4 + 0) * SP + p] = xv0 + d0;
    xT[(qd * 4 + 1) * SP + p] = xv1 + d1;
    xT[(qd * 4 + 2) * SP + p] = xv2 + d2;
    xT[(qd * 4 + 3) * SP + p] = xv3 + d3;
  }

  // loss: wave -> block -> one device atomic; last block finalizes out[0]
#pragma unroll
  for (int off = 1; off < 64; off <<= 1) lp += __shfl_xor(lp, off);
  if ((t & 63) == 0) redbuf[t >> 6] = lp;
  __syncthreads();   // also orders xT rewrites before the stores below
  if (t == 0) {
    float part = 0.f;
#pragma unroll
    for (int w = 0; w < 8; ++w) part += redbuf[w];
    atomicAdd(loss_acc, part);
    __threadfence();
    unsigned old = atomicAdd(cnt, 1u);
    if (old == 255u) {
      __threadfence();
      float total = atomicAdd(loss_acc, 0.0f);  // coherent read-back
      float m = total * (1.0f / 2097152.0f);
      out[0] = m + 0.25f * m;                   // ref op order
    }
  }

  // quantized output [B,D,H,W]: scalar coalesced stores (out+1 is 4B-aligned)
  float* outq = out + 1 + b * (D_ * HW) + hw0;
#pragma unroll
  for (int i = 0; i < 16; ++i) {
    int oi = t + i * 512;                 // 0..8191
    int d = oi >> 7, p = oi & 127;
    outq[d * HW + p] = xT[d * SP + p];
  }
}

extern "C" void kernel_launch(void* const* d_in, const int* in_sizes, int n_in,
                              void* d_out, int out_size, void* d_ws, size_t ws_size,
                              hipStream_t stream) {
  const float* in  = (const float*)d_in[0];
  const float* emb = (const float*)d_in[1];
  float* out = (float*)d_out;
  float* loss_acc = (float*)d_ws;                 // ws[0]
  unsigned* cnt   = (unsigned*)d_ws + 4;          // ws[4]

  hipMemsetAsync(d_ws, 0, 64, stream);            // zero accumulator + counter
  vq_main_kernel<<<256, 512, 0, stream>>>(in, emb, out, loss_acc, cnt);
}